// Round 3
// baseline (19382.918 us; speedup 1.0000x reference)
//
#include <hip/hip_runtime.h>
#include <hip/hip_bf16.h>

#define NLAY 8
#define TT 17

template <bool BF16>
__device__ __forceinline__ float ld(const void* p, int i) {
  if (BF16) return __bfloat162float(((const __hip_bfloat16*)p)[i]);
  return ((const float*)p)[i];
}

// load elements i, i+1 (i must be even)
template <bool BF16>
__device__ __forceinline__ float2 ld2(const void* p, int i) {
  float2 r;
  if (BF16) {
    unsigned u = ((const unsigned*)p)[i >> 1];
    r.x = __uint_as_float(u << 16);
    r.y = __uint_as_float(u & 0xffff0000u);
  } else {
    r = ((const float2*)p)[i >> 1];
  }
  return r;
}

__device__ __forceinline__ unsigned pack_bf2(float a, float b) {
  __hip_bfloat16 ha = __float2bfloat16(a), hb = __float2bfloat16(b);
  unsigned short ua, ub;
  __builtin_memcpy(&ua, &ha, 2);
  __builtin_memcpy(&ub, &hb, 2);
  return ((unsigned)ub << 16) | (unsigned)ua;
}

// ws[0..271]=sin (17x16), ws[272..543]=cos, ws[544..1699]=dmask (4x17x17),
// ws[1700]=dtype flag (1.0 = bf16 storage, 0.0 = fp32 storage)
__global__ void setup_tables(float* __restrict__ ws, const void* __restrict__ x) {
  int tid = threadIdx.x;
  for (int idx = tid; idx < 272; idx += 256) {
    int t = idx >> 4, j = idx & 15;
    float a = powf(10000.f, -(float)(j >> 1) / 7.f);
    float arg = (float)t * a;
    ws[idx] = sinf(arg);
    ws[272 + idx] = cosf(arg);
  }
  for (int row = tid; row < 68; row += 256) {
    int hh = row / 17, t = row % 17;
    float gamma = 1.f - exp2f(-5.f - 4.f * (float)hh / 3.f);
    float sum = 0.f;
    for (int u = 0; u <= t; ++u) sum += powf(gamma, (float)(t - u));
    float rn = rsqrtf(sum);
    for (int u = 0; u < 17; ++u)
      ws[544 + row * 17 + u] = (u <= t) ? powf(gamma, (float)(t - u)) * rn : 0.f;
  }
  if (tid == 0) {
    const unsigned short* u16 = (const unsigned short*)x;
    int sane = 0;
    for (int i = 0; i < 128; ++i) {
      unsigned int bits = ((unsigned int)u16[2 * i]) << 16;
      float v = __uint_as_float(bits);
      float av = fabsf(v);
      if (v == 0.f || (av > 1e-8f && av < 1e4f)) sane++;
    }
    ws[1700] = (sane >= 64) ? 1.f : 0.f;
  }
}

// LDS layout (floats), total 9776 = 39.1 KB -> 4 blocks/CU
#define O_XNO 0      // 2176: XN (17x64) aliased with OO (17x128)
#define O_SC  2176   // 1156: scores 4x17x17
#define O_H   3332   // 1088: residual
#define O_Q   4420   // 1088: Q linear (17x64)
#define O_KT  5508   // 1088: K transposed (64x17)
#define O_VB  6596   // 1088 float-equiv: V bf16 (17x128)
#define O_GB  7684   // 1088 float-equiv: G bf16
#define O_SIN 8772   // 272
#define O_COS 9044   // 272
#define O_FF  9316   // 204
#define O_ST  9520   // 256 stats
#define SM_TOT 9776

template <bool BF16>
__global__ void __launch_bounds__(256, 4)
vit_fused(const void* __restrict__ x,
          const void* __restrict__ patch_w,
          const void* __restrict__ patch_b,
          const void* __restrict__ cls,
          const void* __restrict__ pos,
          const void* __restrict__ Wq,
          const void* __restrict__ Wk,
          const void* __restrict__ Wv,
          const void* __restrict__ Wg,
          const void* __restrict__ Wo,
          const void* __restrict__ ln1s,
          const void* __restrict__ ln1b,
          const void* __restrict__ w1,
          const void* __restrict__ b1,
          const void* __restrict__ w2,
          const void* __restrict__ b2,
          const void* __restrict__ ln2s,
          const void* __restrict__ ln2b,
          const void* __restrict__ lnfs,
          const void* __restrict__ lnfb,
          const void* __restrict__ neckw,
          const void* __restrict__ neckb,
          const void* __restrict__ headw,
          const void* __restrict__ headb,
          const float* __restrict__ tab,
          void* __restrict__ out) {
  if ((tab[1700] > 0.5f) != BF16) return;

  const int b = blockIdx.x;
  const int tid = threadIdx.x;

  __shared__ __align__(16) float sm[SM_TOT];
  float* sXNO = sm + O_XNO;
  float* sSC  = sm + O_SC;
  float* sH   = sm + O_H;
  float* sQ   = sm + O_Q;
  float* sKT  = sm + O_KT;
  __hip_bfloat16* sVb = (__hip_bfloat16*)(sm + O_VB);
  __hip_bfloat16* sGb = (__hip_bfloat16*)(sm + O_GB);
  float* sSin = sm + O_SIN;
  float* sCos = sm + O_COS;
  float* sFF  = sm + O_FF;
  float* sST  = sm + O_ST;
  float* sPX  = sm + O_XNO;  // 3072 pixels alias XNO+SC (dead until layer loop)

  const float* tabDM = tab + 544;
  const float4* xn4 = (const float4*)sXNO;
  const float4* oo4 = (const float4*)sXNO;

  // ---- stage image + tables ----
  for (int i = tid; i < 3072; i += 256) sPX[i] = ld<BF16>(x, b * 3072 + i);
  for (int i = tid; i < 272; i += 256) { sSin[i] = tab[i]; sCos[i] = tab[272 + i]; }
  __syncthreads();

  // ---- patch embed + cls + pos -> sH (column pairs) ----
  for (int idx = tid; idx < 544; idx += 256) {
    int t = idx >> 5, dp = idx & 31, d0 = dp * 2;
    float a0, a1;
    if (t == 0) {
      float2 cv = ld2<BF16>(cls, d0);
      a0 = cv.x; a1 = cv.y;
    } else {
      float2 pb = ld2<BF16>(patch_b, d0);
      a0 = pb.x; a1 = pb.y;
      int p = t - 1, pi = p >> 2, pj = p & 3;
      for (int c = 0; c < 3; ++c)
        for (int a = 0; a < 8; ++a) {
          const float* px = sPX + c * 1024 + (pi * 8 + a) * 32 + pj * 8;
          int wrow = (c * 64 + a * 8) * 64 + d0;
#pragma unroll
          for (int bb = 0; bb < 8; ++bb) {
            float pv = px[bb];
            float2 wv = ld2<BF16>(patch_w, wrow + bb * 64);
            a0 += pv * wv.x;
            a1 += pv * wv.y;
          }
        }
    }
    float2 pv2 = ld2<BF16>(pos, t * 64 + d0);
    sH[t * 64 + d0] = a0 + pv2.x;
    sH[t * 64 + d0 + 1] = a1 + pv2.y;
  }
  __syncthreads();

  for (int l = 0; l < NLAY; ++l) {
    const int oQ = l * 64 * 64;
    const int oV = l * 64 * 128;
    const int oO = l * 128 * 64;

    // ---- ln1 (lane-rotated reads: bank = (dd+tid)%32 distinct) ----
    if (tid < TT) {
      float s1 = 0.f, s2 = 0.f;
      int rot = tid & 63;
      for (int dd = 0; dd < 64; ++dd) {
        int d = (dd + rot) & 63;
        float v = sH[tid * 64 + d];
        s1 += v; s2 += v * v;
      }
      float mu = s1 * (1.f / 64.f);
      float var = s2 * (1.f / 64.f) - mu * mu;
      sST[tid] = mu;
      sST[17 + tid] = rsqrtf(var + 1e-5f);
    }
    __syncthreads();
    for (int idx = tid; idx < TT * 64; idx += 256) {
      int t = idx >> 6, d = idx & 63;
      sXNO[idx] = (sH[idx] - sST[t]) * sST[17 + t] * ld<BF16>(ln1s, l * 64 + d) +
                  ld<BF16>(ln1b, l * 64 + d);
    }
    __syncthreads();

    // ---- q,k,v,g projections: 192 threads x column-pairs, pipelined float2 loads ----
    if (tid < 192) {
      const int col = tid * 2;
      const void* W; int nc, off, kind, j;
      if (col < 64)       { W = Wq; nc = 64;  off = oQ; kind = 0; j = col; }
      else if (col < 128) { W = Wk; nc = 64;  off = oQ; kind = 1; j = col - 64; }
      else if (col < 256) { W = Wv; nc = 128; off = oV; kind = 2; j = col - 128; }
      else                { W = Wg; nc = 128; off = oV; kind = 3; j = col - 256; }
      float acc0[17], acc1[17];
#pragma unroll
      for (int t = 0; t < 17; ++t) { acc0[t] = 0.f; acc1[t] = 0.f; }
      float2 w0 = ld2<BF16>(W, off + 0 * nc + j);
      float2 w1_ = ld2<BF16>(W, off + 1 * nc + j);
      float2 w2_ = ld2<BF16>(W, off + 2 * nc + j);
      float2 w3_ = ld2<BF16>(W, off + 3 * nc + j);
      for (int d4 = 0; d4 < 16; ++d4) {
        int nb = off + ((d4 < 15) ? (d4 * 4 + 4) : 0) * nc + j;
        float2 n0 = ld2<BF16>(W, nb);
        float2 n1 = ld2<BF16>(W, nb + nc);
        float2 n2 = ld2<BF16>(W, nb + 2 * nc);
        float2 n3 = ld2<BF16>(W, nb + 3 * nc);
#pragma unroll
        for (int t = 0; t < 17; ++t) {
          float4 xv = xn4[t * 16 + d4];
          acc0[t] += xv.x * w0.x + xv.y * w1_.x + xv.z * w2_.x + xv.w * w3_.x;
          acc1[t] += xv.x * w0.y + xv.y * w1_.y + xv.z * w2_.y + xv.w * w3_.y;
        }
        w0 = n0; w1_ = n1; w2_ = n2; w3_ = n3;
      }
      if (kind == 0) {
#pragma unroll
        for (int t = 0; t < 17; ++t) {
          float2 v; v.x = acc0[t]; v.y = acc1[t];
          *(float2*)(sQ + t * 64 + j) = v;
        }
      } else if (kind == 1) {
#pragma unroll
        for (int t = 0; t < 17; ++t) {
          sKT[j * 17 + t] = acc0[t];
          sKT[(j + 1) * 17 + t] = acc1[t];
        }
      } else {
        unsigned* dstp = (unsigned*)(kind == 2 ? (void*)sVb : (void*)sGb);
#pragma unroll
        for (int t = 0; t < 17; ++t) dstp[(t * 128 + j) >> 1] = pack_bf2(acc0[t], acc1[t]);
      }
    }
    __syncthreads();

    // ---- rotary: Q in-place linear, K in-place transposed (*0.25) ----
    for (int idx = tid; idx < 1088; idx += 256) {
      if (idx < 544) {
        int t = idx >> 5, pr = idx & 31, d0 = 2 * pr, jj = d0 & 15;
        float sv = sSin[t * 16 + jj], cv = sCos[t * 16 + jj];
        float x0 = sQ[t * 64 + d0], x1 = sQ[t * 64 + d0 + 1];
        sQ[t * 64 + d0] = x0 * cv - x1 * sv;
        sQ[t * 64 + d0 + 1] = x1 * cv + x0 * sv;
      } else {
        int r = idx - 544;
        int t = r >> 5, pr = r & 31, d0 = 2 * pr, jj = d0 & 15;
        float sv = sSin[t * 16 + jj], cv = sCos[t * 16 + jj];
        int a0 = d0 * 17 + t, a1 = (d0 + 1) * 17 + t;
        float x0 = sKT[a0], x1 = sKT[a1];
        sKT[a0] = (x0 * cv - x1 * sv) * 0.25f;
        sKT[a1] = (x1 * cv + x0 * sv) * 0.25f;
      }
    }
    __syncthreads();

    // ---- scores = (q.k)*dmask ; K reads stride-1 over u (conflict-free) ----
    for (int idx = tid; idx < 1156; idx += 256) {
      int hh = idx / 289, r = idx % 289, t = r / 17, u = r % 17;
      float acc = 0.f;
      if (u <= t) {
        const float4* q4 = (const float4*)(sQ + t * 64 + hh * 16);
        const float* kp = sKT + hh * 272 + u;
        float4 qa = q4[0], qb = q4[1], qc = q4[2], qd = q4[3];
        acc = qa.x * kp[0]   + qa.y * kp[17]  + qa.z * kp[34]  + qa.w * kp[51]
            + qb.x * kp[68]  + qb.y * kp[85]  + qb.z * kp[102] + qb.w * kp[119]
            + qc.x * kp[136] + qc.y * kp[153] + qc.z * kp[170] + qc.w * kp[187]
            + qd.x * kp[204] + qd.y * kp[221] + qd.z * kp[238] + qd.w * kp[255];
        acc *= tabDM[idx];
      }
      sSC[idx] = acc;
    }
    __syncthreads();

    // ---- row denominators ----
    if (tid < 68) {
      int base = tid * 17;
      float s = 0.f;
      for (int u = 0; u < 17; ++u) s += sSC[base + u];
      float den = fabsf(s);
      if (den < 1.f) den = 1.f;
      sST[34 + tid] = 1.f / den;
    }
    __syncthreads();

    // ---- o = (scores/denom) @ v -> sXNO (as OO, 17x128) ----
    for (int idx = tid; idx < 2176; idx += 256) {
      int hh = idx / 544, r = idx % 544, t = r >> 5, j = r & 31;
      const float* sc = sSC + hh * 289 + t * 17;
      const __hip_bfloat16* vp = sVb + hh * 32 + j;
      float acc = 0.f;
#pragma unroll
      for (int u = 0; u < 17; ++u)
        acc += sc[u] * __bfloat162float(vp[u * 128]);
      sXNO[t * 128 + hh * 32 + j] = acc * sST[34 + hh * 17 + t];
    }
    __syncthreads();

    // ---- group norm stats (lane-rotated) ----
    if (tid < 68) {
      int hh = tid / 17, t = tid % 17;
      int rot = tid & 31;
      float s1 = 0.f, s2 = 0.f;
      for (int jj = 0; jj < 32; ++jj) {
        int j = (jj + rot) & 31;
        float v = sXNO[t * 128 + hh * 32 + j];
        s1 += v; s2 += v * v;
      }
      float mu = s1 * (1.f / 32.f);
      float var = s2 * (1.f / 32.f) - mu * mu;
      sST[102 + tid] = mu;
      sST[170 + tid] = rsqrtf(var + 1e-5f);
    }
    __syncthreads();
    // ---- normalize + silu(g) gate ----
    for (int idx = tid; idx < 2176; idx += 256) {
      int t = idx >> 7, c = idx & 127, hh = c >> 5;
      float on = (sXNO[idx] - sST[102 + hh * 17 + t]) * sST[170 + hh * 17 + t];
      float gv = __bfloat162float(sGb[idx]);
      float sil = gv / (1.f + __expf(-gv));
      sXNO[idx] = sil * on;
    }
    __syncthreads();

    // ---- @ Wo (128->64) + residual; d-pairs, pipelined ----
    {
      const int dp = tid & 31, tq = tid >> 5;  // tq 0..7
      const int d0 = dp * 2;
      float a00 = 0, a01 = 0, a10 = 0, a11 = 0, a20 = 0, a21 = 0;
      float2 w0 = ld2<BF16>(Wo, oO + 0 * 64 + d0);
      float2 w1_ = ld2<BF16>(Wo, oO + 1 * 64 + d0);
      float2 w2_ = ld2<BF16>(Wo, oO + 2 * 64 + d0);
      float2 w3_ = ld2<BF16>(Wo, oO + 3 * 64 + d0);
      for (int c4 = 0; c4 < 32; ++c4) {
        int nb = oO + ((c4 < 31) ? (c4 * 4 + 4) : 0) * 64 + d0;
        float2 n0 = ld2<BF16>(Wo, nb);
        float2 n1 = ld2<BF16>(Wo, nb + 64);
        float2 n2 = ld2<BF16>(Wo, nb + 128);
        float2 n3 = ld2<BF16>(Wo, nb + 192);
        float4 ov = oo4[tq * 32 + c4];
        a00 += ov.x * w0.x + ov.y * w1_.x + ov.z * w2_.x + ov.w * w3_.x;
        a01 += ov.x * w0.y + ov.y * w1_.y + ov.z * w2_.y + ov.w * w3_.y;
        ov = oo4[(tq + 8) * 32 + c4];
        a10 += ov.x * w0.x + ov.y * w1_.x + ov.z * w2_.x + ov.w * w3_.x;
        a11 += ov.x * w0.y + ov.y * w1_.y + ov.z * w2_.y + ov.w * w3_.y;
        if (tq == 0) {
          ov = oo4[16 * 32 + c4];
          a20 += ov.x * w0.x + ov.y * w1_.x + ov.z * w2_.x + ov.w * w3_.x;
          a21 += ov.x * w0.y + ov.y * w1_.y + ov.z * w2_.y + ov.w * w3_.y;
        }
        w0 = n0; w1_ = n1; w2_ = n2; w3_ = n3;
      }
      sH[tq * 64 + d0] += a00;
      sH[tq * 64 + d0 + 1] += a01;
      sH[(tq + 8) * 64 + d0] += a10;
      sH[(tq + 8) * 64 + d0 + 1] += a11;
      if (tq == 0) {
        sH[16 * 64 + d0] += a20;
        sH[16 * 64 + d0 + 1] += a21;
      }
    }
    __syncthreads();

    // ---- ln2 ----
    if (tid < TT) {
      float s1 = 0.f, s2 = 0.f;
      int rot = tid & 63;
      for (int dd = 0; dd < 64; ++dd) {
        int d = (dd + rot) & 63;
        float v = sH[tid * 64 + d];
        s1 += v; s2 += v * v;
      }
      float mu = s1 * (1.f / 64.f);
      float var = s2 * (1.f / 64.f) - mu * mu;
      sST[tid] = mu;
      sST[17 + tid] = rsqrtf(var + 1e-5f);
    }
    __syncthreads();
    for (int idx = tid; idx < TT * 64; idx += 256) {
      int t = idx >> 6, d = idx & 63;
      sXNO[idx] = (sH[idx] - sST[t]) * sST[17 + t] * ld<BF16>(ln2s, l * 64 + d) +
                  ld<BF16>(ln2b, l * 64 + d);
    }
    __syncthreads();

    // ---- FFN up (64->12) e-pairs + gelu ----
    if (tid < 102) {
      int t = tid / 6, ep = tid % 6, e0 = 2 * ep;
      float2 bb = ld2<BF16>(b1, l * 12 + e0);
      float a0 = bb.x, a1 = bb.y;
      for (int d4 = 0; d4 < 16; ++d4) {
        float4 xv = xn4[t * 16 + d4];
        float2 w0 = ld2<BF16>(w1, (l * 64 + d4 * 4 + 0) * 12 + e0);
        float2 w1v = ld2<BF16>(w1, (l * 64 + d4 * 4 + 1) * 12 + e0);
        float2 w2v = ld2<BF16>(w1, (l * 64 + d4 * 4 + 2) * 12 + e0);
        float2 w3v = ld2<BF16>(w1, (l * 64 + d4 * 4 + 3) * 12 + e0);
        a0 += xv.x * w0.x + xv.y * w1v.x + xv.z * w2v.x + xv.w * w3v.x;
        a1 += xv.x * w0.y + xv.y * w1v.y + xv.z * w2v.y + xv.w * w3v.y;
      }
      float i0 = 0.7978845608028654f * (a0 + 0.044715f * a0 * a0 * a0);
      float i1 = 0.7978845608028654f * (a1 + 0.044715f * a1 * a1 * a1);
      sFF[t * 12 + e0] = 0.5f * a0 * (1.f + tanhf(i0));
      sFF[t * 12 + e0 + 1] = 0.5f * a1 * (1.f + tanhf(i1));
    }
    __syncthreads();

    // ---- FFN down (12->64) d-pairs + residual ----
    for (int idx = tid; idx < 544; idx += 256) {
      int t = idx >> 5, dp = idx & 31, d0 = 2 * dp;
      float2 bb = ld2<BF16>(b2, l * 64 + d0);
      float a0 = bb.x, a1 = bb.y;
#pragma unroll
      for (int e = 0; e < 12; ++e) {
        float fv = sFF[t * 12 + e];
        float2 wv = ld2<BF16>(w2, (l * 12 + e) * 64 + d0);
        a0 += fv * wv.x;
        a1 += fv * wv.y;
      }
      sH[t * 64 + d0] += a0;
      sH[t * 64 + d0 + 1] += a1;
    }
    __syncthreads();
  }

  // ---- final: lnf on last token, neck, head ----
  if (tid == 0) {
    float s1 = 0.f, s2 = 0.f;
    for (int d = 0; d < 64; ++d) { float v = sH[16 * 64 + d]; s1 += v; s2 += v * v; }
    float mu = s1 * (1.f / 64.f);
    float var = s2 * (1.f / 64.f) - mu * mu;
    sST[0] = mu;
    sST[1] = rsqrtf(var + 1e-5f);
  }
  __syncthreads();
  if (tid < 16) {
    float acc = ld<BF16>(neckb, tid);
    for (int d = 0; d < 64; ++d) {
      float yn = (sH[16 * 64 + d] - sST[0]) * sST[1] * ld<BF16>(lnfs, d) + ld<BF16>(lnfb, d);
      acc += yn * ld<BF16>(neckw, d * 16 + tid);
    }
    sST[2 + tid] = acc;
  }
  __syncthreads();
  if (tid < 10) {
    float acc = ld<BF16>(headb, tid);
#pragma unroll
    for (int e = 0; e < 16; ++e) acc += sST[2 + e] * ld<BF16>(headw, e * 10 + tid);
    if (BF16) ((__hip_bfloat16*)out)[b * 10 + tid] = __float2bfloat16(acc);
    else      ((float*)out)[b * 10 + tid] = acc;
  }
}

extern "C" void kernel_launch(void* const* d_in, const int* in_sizes, int n_in,
                              void* d_out, int out_size, void* d_ws, size_t ws_size,
                              hipStream_t stream) {
  float* tab = (float*)d_ws;
  setup_tables<<<dim3(1), dim3(256), 0, stream>>>(tab, d_in[0]);

  const int B = in_sizes[0] / (3 * 32 * 32);
  const void* in[24];
  for (int i = 0; i < 24; ++i) in[i] = d_in[i];

  vit_fused<false><<<dim3(B), dim3(256), 0, stream>>>(
      in[0], in[1], in[2], in[3], in[4], in[5], in[6], in[7], in[8], in[9],
      in[10], in[11], in[12], in[13], in[14], in[15], in[16], in[17], in[18],
      in[19], in[20], in[21], in[22], in[23], (const float*)tab, d_out);
  vit_fused<true><<<dim3(B), dim3(256), 0, stream>>>(
      in[0], in[1], in[2], in[3], in[4], in[5], in[6], in[7], in[8], in[9],
      in[10], in[11], in[12], in[13], in[14], in[15], in[16], in[17], in[18],
      in[19], in[20], in[21], in[22], in[23], (const float*)tab, d_out);
}

// Round 4
// 1955.581 us; speedup vs baseline: 9.9116x; 9.9116x over previous
//
#include <hip/hip_runtime.h>
#include <hip/hip_bf16.h>

#define NLAY 8
#define MFMA __builtin_amdgcn_mfma_f32_16x16x32_bf16

typedef __attribute__((ext_vector_type(8))) short bf16x8;
typedef __attribute__((ext_vector_type(4))) float f32x4;
typedef __attribute__((ext_vector_type(4))) int i32x4;

template <bool BF16>
__device__ __forceinline__ float ld(const void* p, int i) {
  if (BF16) {
    unsigned short u = ((const unsigned short*)p)[i];
    return __uint_as_float(((unsigned)u) << 16);
  }
  return ((const float*)p)[i];
}

template <bool BF16>
__device__ __forceinline__ float2 ld2(const void* p, int i) {  // i even
  float2 r;
  if (BF16) {
    unsigned u = ((const unsigned*)p)[i >> 1];
    r.x = __uint_as_float(u << 16);
    r.y = __uint_as_float(u & 0xffff0000u);
  } else {
    r = ((const float2*)p)[i >> 1];
  }
  return r;
}

__device__ __forceinline__ float bfu(unsigned short u) {
  return __uint_as_float(((unsigned)u) << 16);
}

__device__ __forceinline__ unsigned pack_bf2(float a, float b) {
  __hip_bfloat16 ha = __float2bfloat16(a), hb = __float2bfloat16(b);
  unsigned short ua, ub;
  __builtin_memcpy(&ua, &ha, 2);
  __builtin_memcpy(&ub, &hb, 2);
  return ((unsigned)ub << 16) | (unsigned)ua;
}

__device__ __forceinline__ float2 unpk(unsigned u) {
  float2 r;
  r.x = __uint_as_float(u << 16);
  r.y = __uint_as_float(u & 0xffff0000u);
  return r;
}

// ws[0..271]=sin, ws[272..543]=cos, ws[544..1699]=dmask, ws[1700]=dtype flag
__global__ void setup_tables(float* __restrict__ ws, const void* __restrict__ x) {
  int tid = threadIdx.x;
  for (int idx = tid; idx < 272; idx += 256) {
    int t = idx >> 4, j = idx & 15;
    float a = powf(10000.f, -(float)(j >> 1) / 7.f);
    float arg = (float)t * a;
    ws[idx] = sinf(arg);
    ws[272 + idx] = cosf(arg);
  }
  for (int row = tid; row < 68; row += 256) {
    int hh = row / 17, t = row % 17;
    float gamma = 1.f - exp2f(-5.f - 4.f * (float)hh / 3.f);
    float sum = 0.f;
    for (int u = 0; u <= t; ++u) sum += powf(gamma, (float)(t - u));
    float rn = rsqrtf(sum);
    for (int u = 0; u < 17; ++u)
      ws[544 + row * 17 + u] = (u <= t) ? powf(gamma, (float)(t - u)) * rn : 0.f;
  }
  if (tid == 0) {
    const unsigned short* u16 = (const unsigned short*)x;
    int sane = 0;
    for (int i = 0; i < 128; ++i) {
      float v = __uint_as_float(((unsigned)u16[2 * i]) << 16);
      float av = fabsf(v);
      if (v == 0.f || (av > 1e-8f && av < 1e4f)) sane++;
    }
    ws[1700] = (sane >= 64) ? 1.f : 0.f;
  }
}

// Pre-swizzle weights into MFMA B-fragment order (bf16), into ws+8192 bytes.
// Frag element (nt,kt,lane,j): n=nt*16+(lane&15), k=kt*32+(lane>>4)*8+j, src=W[k][n].
// Layout (ushort idx): PW[12288] | per layer(33536): Wq 4096|Wk 4096|Wv 8192|
//   Wg 8192|Wo 8192|w1T 768 (plain transposed 12x64).
#define FRAG_TOT 280576
template <bool BF16>
__global__ void prep_frags(const void* __restrict__ patch_w,
                           const void* __restrict__ Wq, const void* __restrict__ Wk,
                           const void* __restrict__ Wv, const void* __restrict__ Wg,
                           const void* __restrict__ Wo, const void* __restrict__ w1,
                           const float* __restrict__ tab,
                           unsigned short* __restrict__ frag) {
  if ((tab[1700] > 0.5f) != BF16) return;
  int g = blockIdx.x * 256 + threadIdx.x;
  if (g >= FRAG_TOT) return;
  float v;
  if (g < 12288) {  // patch_w: K=192 (kt6), N=64 (nt4)
    int nt = g / 3072, r = g % 3072, kt = r / 512, r2 = r % 512, la = r2 >> 3, j = r2 & 7;
    int n = nt * 16 + (la & 15), k = kt * 32 + (la >> 4) * 8 + j;
    v = ld<BF16>(patch_w, k * 64 + n);
  } else {
    int gg = g - 12288, l = gg / 33536, o = gg % 33536;
    if (o < 8192) {  // Wq / Wk: K=64 (kt2), N=64 (nt4)
      const void* W = (o < 4096) ? Wq : Wk;
      int e = o & 4095;
      int nt = e / 1024, r = e % 1024, kt = r / 512, r2 = r % 512, la = r2 >> 3, j = r2 & 7;
      int n = nt * 16 + (la & 15), k = kt * 32 + (la >> 4) * 8 + j;
      v = ld<BF16>(W, l * 4096 + k * 64 + n);
    } else if (o < 24576) {  // Wv / Wg: K=64 (kt2), N=128 (nt8)
      const void* W = (o < 16384) ? Wv : Wg;
      int e = (o - 8192) & 8191;
      int nt = e / 1024, r = e % 1024, kt = r / 512, r2 = r % 512, la = r2 >> 3, j = r2 & 7;
      int n = nt * 16 + (la & 15), k = kt * 32 + (la >> 4) * 8 + j;
      v = ld<BF16>(W, l * 8192 + k * 128 + n);
    } else if (o < 32768) {  // Wo: K=128 (kt4), N=64 (nt4)
      int e = o - 24576;
      int nt = e / 2048, r = e % 2048, kt = r / 512, r2 = r % 512, la = r2 >> 3, j = r2 & 7;
      int n = nt * 16 + (la & 15), k = kt * 32 + (la >> 4) * 8 + j;
      v = ld<BF16>(Wo, l * 8192 + k * 64 + n);
    } else {  // w1T[e][d] = w1[d][e]
      int e = o - 32768, eo = e / 64, d = e % 64;
      v = ld<BF16>(w1, l * 768 + d * 12 + eo);
    }
  }
  __hip_bfloat16 h = __float2bfloat16(v);
  unsigned short us;
  __builtin_memcpy(&us, &h, 2);
  frag[g] = us;
}

// LDS float offsets
#define O_DM   0      // 1156
#define O_SIN  1156   // 272
#define O_COS  1428   // 272
#define O_ST   1700   // 512: lnMu[34] lnR[34] den[136] gnMu[136] gnR[136]
#define O_H    2212   // 2244: H fp32 34x66
#define O_XNF  4456   // 1536: XN A-frags (3mt x 2kt x 64 x 16B) / alias XNp bf16 34x72
#define O_FF   5992   // 408
#define O_R    6400   // 4488: Q fp32 34x68 + KT fp32 2x64x17 / alias O fp32 34x130
#define O_SCA  10888  // 3072: patch A-frags / SC fp32 2312 / OA-frags (3mt x 4kt x 64 x 16B)
#define O_VG   13960  // 4624: V bf16 34x136 + G bf16 34x136
#define SM_TOT 18584

template <bool BF16>
__global__ void __launch_bounds__(256)
vit_fused(const void* __restrict__ x, const void* __restrict__ patch_b,
          const void* __restrict__ cls, const void* __restrict__ pos,
          const void* __restrict__ ln1s, const void* __restrict__ ln1b,
          const void* __restrict__ b1, const void* __restrict__ w2,
          const void* __restrict__ b2, const void* __restrict__ ln2s,
          const void* __restrict__ ln2b, const void* __restrict__ lnfs,
          const void* __restrict__ lnfb, const void* __restrict__ neckw,
          const void* __restrict__ neckb, const void* __restrict__ headw,
          const void* __restrict__ headb, const float* __restrict__ tab,
          const unsigned short* __restrict__ FR, void* __restrict__ out) {
  if ((tab[1700] > 0.5f) != BF16) return;

  const int tid = threadIdx.x;
  const int lane = tid & 63, w = tid >> 6;
  const int lq = lane >> 4, ln = lane & 15;
  const int img0 = 2 * blockIdx.x;

  __shared__ __align__(16) float sm[SM_TOT];
  float* sDM  = sm + O_DM;
  float* sSin = sm + O_SIN;
  float* sCos = sm + O_COS;
  float* sST  = sm + O_ST;
  float* sH   = sm + O_H;
  float* sFF  = sm + O_FF;
  float* sQ   = sm + O_R;          // 34x68
  float* sKT  = sm + O_R + 2312;   // 2x64x17
  float* sO   = sm + O_R;          // alias, 34x130
  float* sSC  = sm + O_SCA;        // 2312
  unsigned short* sVb = (unsigned short*)(sm + O_VG);          // 34x136
  unsigned short* sGb = (unsigned short*)(sm + O_VG) + 4624;   // 34x136
  const bf16x8* FRB = (const bf16x8*)FR;

  // ---- stage tables + patch A-frags + cls rows ----
  for (int i = tid; i < 1156; i += 256) sDM[i] = tab[544 + i];
  for (int i = tid; i < 272; i += 256) { sSin[i] = tab[i]; sCos[i] = tab[272 + i]; }
  for (int s = tid; s < 768; s += 256) {  // patch A-frags into O_SCA
    int mt = s / 384, r = s % 384, kt = r / 64, la = r % 64;
    int p = la & 15, q = la >> 4;
    int kb = kt * 32 + q * 8;
    int c = kb >> 6, rem = kb & 63, a = rem >> 3;
    int pi = p >> 2, pj = p & 3;
    int src = (img0 + mt) * 3072 + c * 1024 + (pi * 8 + a) * 32 + pj * 8;
    float v[8];
#pragma unroll
    for (int t2 = 0; t2 < 8; t2 += 2) {
      float2 pv = ld2<BF16>(x, src + t2);
      v[t2] = pv.x; v[t2 + 1] = pv.y;
    }
    i32x4 pk;
    pk.x = pack_bf2(v[0], v[1]); pk.y = pack_bf2(v[2], v[3]);
    pk.z = pack_bf2(v[4], v[5]); pk.w = pack_bf2(v[6], v[7]);
    ((i32x4*)(sm + O_SCA))[s] = pk;
  }
  if (tid < 128) {  // cls token rows
    int img = tid >> 6, n = tid & 63;
    sH[(img * 17) * 66 + n] = ld<BF16>(cls, n) + ld<BF16>(pos, n);
  }
  __syncthreads();

  // ---- patch embed MFMA: M=32 (2mt), N=64 (4nt), K=192 (6kt) ----
  for (int j = w; j < 8; j += 4) {
    int mt = j >> 2, nt = j & 3;
    f32x4 acc = {0.f, 0.f, 0.f, 0.f};
    const bf16x8* paf = (const bf16x8*)(sm + O_SCA);
#pragma unroll
    for (int kt = 0; kt < 6; ++kt)
      acc = MFMA(paf[(mt * 6 + kt) * 64 + lane], FRB[(nt * 6 + kt) * 64 + lane], acc, 0, 0, 0);
    int n = nt * 16 + ln;
    float pb = ld<BF16>(patch_b, n);
#pragma unroll
    for (int i = 0; i < 4; ++i) {
      int t = 1 + lq * 4 + i;
      sH[(mt * 17 + t) * 66 + n] = acc[i] + pb + ld<BF16>(pos, t * 64 + n);
    }
  }
  __syncthreads();

  for (int l = 0; l < NLAY; ++l) {
    const int LB = 1536 + l * 4192;  // layer base, bf16x8 slots

    // ---- ln1 stats ----
    if (tid < 34) {
      float s1 = 0.f, s2 = 0.f;
      int rot = tid & 63;
      for (int dd = 0; dd < 64; ++dd) {
        int d = (dd + rot) & 63;
        float v = sH[tid * 66 + d];
        s1 += v; s2 += v * v;
      }
      float mu = s1 * (1.f / 64.f);
      float var = s2 * (1.f / 64.f) - mu * mu;
      sST[tid] = mu;
      sST[34 + tid] = rsqrtf(var + 1e-5f);
    }
    __syncthreads();

    // ---- ln1 -> XN A-frags (bf16) ----
    for (int s = tid; s < 384; s += 256) {
      int mt = s >> 7, kt = (s >> 6) & 1, la = s & 63;
      int m = mt * 16 + (la & 15), q = la >> 4;
      int kb = kt * 32 + q * 8;
      i32x4 pk = {0, 0, 0, 0};
      if (m < 34) {
        float mu = sST[m], rr = sST[34 + m];
        float vv[8];
#pragma unroll
        for (int t2 = 0; t2 < 8; t2 += 2) {
          float2 sv = ld2<BF16>(ln1s, l * 64 + kb + t2);
          float2 bv = ld2<BF16>(ln1b, l * 64 + kb + t2);
          vv[t2]     = (sH[m * 66 + kb + t2] - mu) * rr * sv.x + bv.x;
          vv[t2 + 1] = (sH[m * 66 + kb + t2 + 1] - mu) * rr * sv.y + bv.y;
        }
        pk.x = pack_bf2(vv[0], vv[1]); pk.y = pack_bf2(vv[2], vv[3]);
        pk.z = pack_bf2(vv[4], vv[5]); pk.w = pack_bf2(vv[6], vv[7]);
      }
      ((i32x4*)(sm + O_XNF))[s] = pk;
    }
    __syncthreads();

    // ---- QKVG MFMA: 72 jobs = 3mt x 24nt (Q4|K4|V8|G8), kt=2 ----
    {
      const bf16x8* xnf = (const bf16x8*)(sm + O_XNF);
      for (int j = w; j < 72; j += 4) {
        int mt = j / 24, nt = j % 24;
        const bf16x8* wf; int ntl, dst;
        if (nt < 4)       { wf = FRB + LB;        ntl = nt;      dst = 0; }
        else if (nt < 8)  { wf = FRB + LB + 512;  ntl = nt - 4;  dst = 1; }
        else if (nt < 16) { wf = FRB + LB + 1024; ntl = nt - 8;  dst = 2; }
        else              { wf = FRB + LB + 2048; ntl = nt - 16; dst = 3; }
        f32x4 acc = {0.f, 0.f, 0.f, 0.f};
#pragma unroll
        for (int kt = 0; kt < 2; ++kt)
          acc = MFMA(xnf[(mt * 2 + kt) * 64 + lane], wf[(ntl * 2 + kt) * 64 + lane], acc, 0, 0, 0);
        int n = ntl * 16 + ln;
        if (dst == 0) {
#pragma unroll
          for (int i = 0; i < 4; ++i) {
            int m = mt * 16 + lq * 4 + i;
            if (m < 34) sQ[m * 68 + n] = acc[i];
          }
        } else if (dst == 1) {
#pragma unroll
          for (int i = 0; i < 4; ++i) {
            int m = mt * 16 + lq * 4 + i;
            if (m < 34) {
              int img = (m >= 17), t = m - img * 17;
              sKT[img * 1088 + n * 17 + t] = acc[i];
            }
          }
        } else {
          unsigned short* db = (dst == 2) ? sVb : sGb;
#pragma unroll
          for (int i = 0; i < 4; ++i) {
            int m = mt * 16 + lq * 4 + i;
            if (m < 34) {
              __hip_bfloat16 hv = __float2bfloat16(acc[i]);
              unsigned short us;
              __builtin_memcpy(&us, &hv, 2);
              db[m * 136 + n] = us;
            }
          }
        }
      }
    }
    __syncthreads();

    // ---- rotary: Q (linear) + KT (transposed, *0.25) ----
    for (int idx = tid; idx < 2176; idx += 256) {
      if (idx < 1088) {
        int m = idx >> 5, pr = idx & 31, d0 = 2 * pr;
        int t = m % 17;
        float sv = sSin[t * 16 + (d0 & 15)], cv = sCos[t * 16 + (d0 & 15)];
        float x0 = sQ[m * 68 + d0], x1 = sQ[m * 68 + d0 + 1];
        sQ[m * 68 + d0]     = x0 * cv - x1 * sv;
        sQ[m * 68 + d0 + 1] = x1 * cv + x0 * sv;
      } else {
        int r = idx - 1088;
        int img = r / 544, r2 = r % 544, pr = r2 / 17, t = r2 % 17, d0 = 2 * pr;
        float sv = sSin[t * 16 + (d0 & 15)], cv = sCos[t * 16 + (d0 & 15)];
        int a0 = img * 1088 + d0 * 17 + t, a1 = a0 + 17;
        float x0 = sKT[a0], x1 = sKT[a1];
        sKT[a0] = (x0 * cv - x1 * sv) * 0.25f;
        sKT[a1] = (x1 * cv + x0 * sv) * 0.25f;
      }
    }
    __syncthreads();

    // ---- scores ----
    for (int idx = tid; idx < 2312; idx += 256) {
      int img = idx / 1156, r2 = idx % 1156;
      int hh = r2 / 289, r = r2 % 289, t = r / 17, u = r % 17;
      float acc = 0.f;
      if (u <= t) {
        const float4* q4 = (const float4*)(sQ + (img * 17 + t) * 68 + hh * 16);
        const float* kp = sKT + img * 1088 + hh * 272 + u;
        float4 qa = q4[0], qb = q4[1], qc = q4[2], qd = q4[3];
        acc = qa.x * kp[0]   + qa.y * kp[17]  + qa.z * kp[34]  + qa.w * kp[51]
            + qb.x * kp[68]  + qb.y * kp[85]  + qb.z * kp[102] + qb.w * kp[119]
            + qc.x * kp[136] + qc.y * kp[153] + qc.z * kp[170] + qc.w * kp[187]
            + qd.x * kp[204] + qd.y * kp[221] + qd.z * kp[238] + qd.w * kp[255];
        acc *= sDM[r2];
      }
      sSC[idx] = acc;
    }
    __syncthreads();

    // ---- denominators ----
    if (tid < 136) {
      const float* base = sSC + tid * 17;
      float s = 0.f;
      for (int u = 0; u < 17; ++u) s += base[u];
      float den = fabsf(s);
      if (den < 1.f) den = 1.f;
      sST[68 + tid] = 1.f / den;
    }
    __syncthreads();

    // ---- AV -> sO (aliases Q/KT; both dead) ----
    for (int idx = tid; idx < 4352; idx += 256) {
      int img = idx / 2176, r = idx % 2176;
      int hh = r / 544, r3 = r % 544, t = r3 >> 5, jj = r3 & 31;
      int c = hh * 32 + jj, m = img * 17 + t;
      const float* sc = sSC + img * 1156 + hh * 289 + t * 17;
      const unsigned short* vp = sVb + img * 17 * 136 + c;
      float acc = 0.f;
#pragma unroll
      for (int u = 0; u < 17; ++u) acc += sc[u] * bfu(vp[u * 136]);
      sO[m * 130 + c] = acc * sST[68 + img * 68 + hh * 17 + t];
    }
    __syncthreads();

    // ---- group norm stats ----
    if (tid < 136) {
      int img = tid / 68, hr = tid % 68, hh = hr / 17, t = hr % 17;
      int m = img * 17 + t, base = m * 130 + hh * 32, rot = tid & 31;
      float s1 = 0.f, s2 = 0.f;
      for (int jj = 0; jj < 32; ++jj) {
        float v = sO[base + ((jj + rot) & 31)];
        s1 += v; s2 += v * v;
      }
      float mu = s1 * (1.f / 32.f);
      float var = s2 * (1.f / 32.f) - mu * mu;
      sST[204 + tid] = mu;
      sST[340 + tid] = rsqrtf(var + 1e-5f);
    }
    __syncthreads();

    // ---- groupnorm + silu gate -> OA frags (aliases SC; dead) ----
    for (int s = tid; s < 768; s += 256) {
      int mt = s >> 8, kt = (s >> 6) & 3, la = s & 63;
      int q = la >> 4, m = mt * 16 + (la & 15);
      int cb = kt * 32 + q * 8;
      i32x4 pk = {0, 0, 0, 0};
      if (m < 34) {
        int img = (m >= 17), t = m - img * 17;
        int sti = img * 68 + kt * 17 + t;
        float mu = sST[204 + sti], rr = sST[340 + sti];
        float vv[8];
#pragma unroll
        for (int q2 = 0; q2 < 8; ++q2) {
          int c = cb + q2;
          float on = (sO[m * 130 + c] - mu) * rr;
          float gv = bfu(sGb[m * 136 + c]);
          vv[q2] = on * (gv / (1.f + __expf(-gv)));
        }
        pk.x = pack_bf2(vv[0], vv[1]); pk.y = pack_bf2(vv[2], vv[3]);
        pk.z = pack_bf2(vv[4], vv[5]); pk.w = pack_bf2(vv[6], vv[7]);
      }
      ((i32x4*)(sm + O_SCA))[s] = pk;
    }
    __syncthreads();

    // ---- Wo MFMA: 12 jobs = 3mt x 4nt, kt=4; += residual ----
    {
      const bf16x8* oaf = (const bf16x8*)(sm + O_SCA);
      const bf16x8* wof = FRB + LB + 3072;
      for (int j = w; j < 12; j += 4) {
        int mt = j / 4, nt = j % 4;
        f32x4 acc = {0.f, 0.f, 0.f, 0.f};
#pragma unroll
        for (int kt = 0; kt < 4; ++kt)
          acc = MFMA(oaf[(mt * 4 + kt) * 64 + lane], wof[(nt * 4 + kt) * 64 + lane], acc, 0, 0, 0);
        int n = nt * 16 + ln;
#pragma unroll
        for (int i = 0; i < 4; ++i) {
          int m = mt * 16 + lq * 4 + i;
          if (m < 34) sH[m * 66 + n] += acc[i];
        }
      }
    }
    __syncthreads();

    // ---- ln2 stats ----
    if (tid < 34) {
      float s1 = 0.f, s2 = 0.f;
      int rot = tid & 63;
      for (int dd = 0; dd < 64; ++dd) {
        int d = (dd + rot) & 63;
        float v = sH[tid * 66 + d];
        s1 += v; s2 += v * v;
      }
      float mu = s1 * (1.f / 64.f);
      float var = s2 * (1.f / 64.f) - mu * mu;
      sST[tid] = mu;
      sST[34 + tid] = rsqrtf(var + 1e-5f);
    }
    __syncthreads();

    // ---- ln2 -> XNp plain bf16 (34 x pitch 72), aliases XNF ----
    for (int idx = tid; idx < 1088; idx += 256) {
      int m = idx >> 5, dp = idx & 31, d0 = 2 * dp;
      float mu = sST[m], rr = sST[34 + m];
      float2 sv = ld2<BF16>(ln2s, l * 64 + d0);
      float2 bv = ld2<BF16>(ln2b, l * 64 + d0);
      float a0 = (sH[m * 66 + d0] - mu) * rr * sv.x + bv.x;
      float a1 = (sH[m * 66 + d0 + 1] - mu) * rr * sv.y + bv.y;
      ((unsigned*)(sm + O_XNF))[m * 36 + dp] = pack_bf2(a0, a1);
    }
    __syncthreads();

    // ---- FFN1 (64->12) + gelu ----
    for (int item = tid; item < 408; item += 256) {
      int m = item / 12, e = item % 12;
      float acc = ld<BF16>(b1, l * 12 + e);
      const float4* xp4 = (const float4*)(sm + O_XNF);
      const i32x4* w1t = (const i32x4*)(FR + 12288 + l * 33536 + 32768 + e * 64);
#pragma unroll
      for (int d4 = 0; d4 < 8; ++d4) {
        float4 xv = xp4[m * 9 + d4];
        i32x4 wv = w1t[d4];
        float2 xa = unpk(__float_as_uint(xv.x)), wa = unpk((unsigned)wv.x);
        float2 xb = unpk(__float_as_uint(xv.y)), wb = unpk((unsigned)wv.y);
        float2 xc = unpk(__float_as_uint(xv.z)), wc = unpk((unsigned)wv.z);
        float2 xd = unpk(__float_as_uint(xv.w)), wd = unpk((unsigned)wv.w);
        acc += xa.x * wa.x + xa.y * wa.y + xb.x * wb.x + xb.y * wb.y
             + xc.x * wc.x + xc.y * wc.y + xd.x * wd.x + xd.y * wd.y;
      }
      float inner = 0.7978845608028654f * (acc + 0.044715f * acc * acc * acc);
      sFF[item] = 0.5f * acc * (1.f + tanhf(inner));
    }
    __syncthreads();

    // ---- FFN2 (12->64) + residual ----
    for (int idx = tid; idx < 1088; idx += 256) {
      int m = idx >> 5, dp = idx & 31, d0 = 2 * dp;
      float2 bv = ld2<BF16>(b2, l * 64 + d0);
      float a0 = bv.x, a1 = bv.y;
      const float* ff = sFF + m * 12;
#pragma unroll
      for (int e = 0; e < 12; ++e) {
        float2 wv = ld2<BF16>(w2, (l * 12 + e) * 64 + d0);
        a0 += ff[e] * wv.x;
        a1 += ff[e] * wv.y;
      }
      sH[m * 66 + d0] += a0;
      sH[m * 66 + d0 + 1] += a1;
    }
    __syncthreads();
  }

  // ---- final: lnf (last token each image), neck, head ----
  if (tid < 2) {
    int m = tid * 17 + 16;
    float s1 = 0.f, s2 = 0.f;
    for (int d = 0; d < 64; ++d) {
      float v = sH[m * 66 + d];
      s1 += v; s2 += v * v;
    }
    float mu = s1 * (1.f / 64.f);
    float var = s2 * (1.f / 64.f) - mu * mu;
    sST[tid] = mu;
    sST[2 + tid] = rsqrtf(var + 1e-5f);
  }
  __syncthreads();
  if (tid < 32) {
    int img = tid >> 4, jn = tid & 15;
    int m = img * 17 + 16;
    float mu = sST[img], rr = sST[2 + img];
    float acc = ld<BF16>(neckb, jn);
    for (int d = 0; d < 64; ++d) {
      float yn = (sH[m * 66 + d] - mu) * rr * ld<BF16>(lnfs, d) + ld<BF16>(lnfb, d);
      acc += yn * ld<BF16>(neckw, d * 16 + jn);
    }
    sST[8 + img * 16 + jn] = acc;
  }
  __syncthreads();
  if (tid < 20) {
    int img = tid / 10, o = tid % 10;
    float acc = ld<BF16>(headb, o);
#pragma unroll
    for (int e = 0; e < 16; ++e) acc += sST[8 + img * 16 + e] * ld<BF16>(headw, e * 10 + o);
    if (BF16) {
      ((__hip_bfloat16*)out)[(img0 + img) * 10 + o] = __float2bfloat16(acc);
    } else {
      ((float*)out)[(img0 + img) * 10 + o] = acc;
    }
  }
}

extern "C" void kernel_launch(void* const* d_in, const int* in_sizes, int n_in,
                              void* d_out, int out_size, void* d_ws, size_t ws_size,
                              hipStream_t stream) {
  float* tab = (float*)d_ws;
  unsigned short* frag = (unsigned short*)((char*)d_ws + 8192);

  setup_tables<<<dim3(1), dim3(256), 0, stream>>>(tab, d_in[0]);

  const int prepBlocks = (FRAG_TOT + 255) / 256;
  prep_frags<false><<<dim3(prepBlocks), dim3(256), 0, stream>>>(
      d_in[1], d_in[5], d_in[6], d_in[7], d_in[8], d_in[9], d_in[12], tab, frag);
  prep_frags<true><<<dim3(prepBlocks), dim3(256), 0, stream>>>(
      d_in[1], d_in[5], d_in[6], d_in[7], d_in[8], d_in[9], d_in[12], tab, frag);

  const int B = in_sizes[0] / 3072;
  const int grid = B / 2;

  vit_fused<false><<<dim3(grid), dim3(256), 0, stream>>>(
      d_in[0], d_in[2], d_in[3], d_in[4], d_in[10], d_in[11], d_in[13],
      d_in[14], d_in[15], d_in[16], d_in[17], d_in[18], d_in[19], d_in[20],
      d_in[21], d_in[22], d_in[23], tab, frag, d_out);
  vit_fused<true><<<dim3(grid), dim3(256), 0, stream>>>(
      d_in[0], d_in[2], d_in[3], d_in[4], d_in[10], d_in[11], d_in[13],
      d_in[14], d_in[15], d_in[16], d_in[17], d_in[18], d_in[19], d_in[20],
      d_in[21], d_in[22], d_in[23], tab, frag, d_out);
}

// Round 5
// 1421.912 us; speedup vs baseline: 13.6316x; 1.3753x over previous
//
#include <hip/hip_runtime.h>
#include <hip/hip_bf16.h>

#define NLAY 8
#define MFMA __builtin_amdgcn_mfma_f32_16x16x32_bf16

typedef __attribute__((ext_vector_type(8))) short bf16x8;
typedef __attribute__((ext_vector_type(4))) float f32x4;
typedef __attribute__((ext_vector_type(4))) int i32x4;

template <bool BF16>
__device__ __forceinline__ float ld(const void* p, int i) {
  if (BF16) {
    unsigned short u = ((const unsigned short*)p)[i];
    return __uint_as_float(((unsigned)u) << 16);
  }
  return ((const float*)p)[i];
}

template <bool BF16>
__device__ __forceinline__ float2 ld2(const void* p, int i) {  // i even
  float2 r;
  if (BF16) {
    unsigned u = ((const unsigned*)p)[i >> 1];
    r.x = __uint_as_float(u << 16);
    r.y = __uint_as_float(u & 0xffff0000u);
  } else {
    r = ((const float2*)p)[i >> 1];
  }
  return r;
}

__device__ __forceinline__ float bfu(unsigned short u) {
  return __uint_as_float(((unsigned)u) << 16);
}

__device__ __forceinline__ unsigned pack_bf2(float a, float b) {
  __hip_bfloat16 ha = __float2bfloat16(a), hb = __float2bfloat16(b);
  unsigned short ua, ub;
  __builtin_memcpy(&ua, &ha, 2);
  __builtin_memcpy(&ub, &hb, 2);
  return ((unsigned)ub << 16) | (unsigned)ua;
}

__device__ __forceinline__ float2 unpk(unsigned u) {
  float2 r;
  r.x = __uint_as_float(u << 16);
  r.y = __uint_as_float(u & 0xffff0000u);
  return r;
}

// ws[0..271]=sin, ws[272..543]=cos, ws[544..1699]=dmask, ws[1700]=dtype flag
__global__ void setup_tables(float* __restrict__ ws, const void* __restrict__ x) {
  int tid = threadIdx.x;
  for (int idx = tid; idx < 272; idx += 256) {
    int t = idx >> 4, j = idx & 15;
    float a = powf(10000.f, -(float)(j >> 1) / 7.f);
    float arg = (float)t * a;
    ws[idx] = sinf(arg);
    ws[272 + idx] = cosf(arg);
  }
  for (int row = tid; row < 68; row += 256) {
    int hh = row / 17, t = row % 17;
    float gamma = 1.f - exp2f(-5.f - 4.f * (float)hh / 3.f);
    float sum = 0.f;
    for (int u = 0; u <= t; ++u) sum += powf(gamma, (float)(t - u));
    float rn = rsqrtf(sum);
    for (int u = 0; u < 17; ++u)
      ws[544 + row * 17 + u] = (u <= t) ? powf(gamma, (float)(t - u)) * rn : 0.f;
  }
  if (tid == 0) {
    const unsigned short* u16 = (const unsigned short*)x;
    int sane = 0;
    for (int i = 0; i < 128; ++i) {
      float v = __uint_as_float(((unsigned)u16[2 * i]) << 16);
      float av = fabsf(v);
      if (v == 0.f || (av > 1e-8f && av < 1e4f)) sane++;
    }
    ws[1700] = (sane >= 64) ? 1.f : 0.f;
  }
}

// Pre-swizzle weights into MFMA B-fragment order (bf16), into ws+8192 bytes.
#define FRAG_TOT 280576
template <bool BF16>
__global__ void prep_frags(const void* __restrict__ patch_w,
                           const void* __restrict__ Wq, const void* __restrict__ Wk,
                           const void* __restrict__ Wv, const void* __restrict__ Wg,
                           const void* __restrict__ Wo, const void* __restrict__ w1,
                           const float* __restrict__ tab,
                           unsigned short* __restrict__ frag) {
  if ((tab[1700] > 0.5f) != BF16) return;
  int g = blockIdx.x * 256 + threadIdx.x;
  if (g >= FRAG_TOT) return;
  float v;
  if (g < 12288) {  // patch_w: K=192 (kt6), N=64 (nt4)
    int nt = g / 3072, r = g % 3072, kt = r / 512, r2 = r % 512, la = r2 >> 3, j = r2 & 7;
    int n = nt * 16 + (la & 15), k = kt * 32 + (la >> 4) * 8 + j;
    v = ld<BF16>(patch_w, k * 64 + n);
  } else {
    int gg = g - 12288, l = gg / 33536, o = gg % 33536;
    if (o < 8192) {  // Wq / Wk
      const void* W = (o < 4096) ? Wq : Wk;
      int e = o & 4095;
      int nt = e / 1024, r = e % 1024, kt = r / 512, r2 = r % 512, la = r2 >> 3, j = r2 & 7;
      int n = nt * 16 + (la & 15), k = kt * 32 + (la >> 4) * 8 + j;
      v = ld<BF16>(W, l * 4096 + k * 64 + n);
    } else if (o < 24576) {  // Wv / Wg
      const void* W = (o < 16384) ? Wv : Wg;
      int e = (o - 8192) & 8191;
      int nt = e / 1024, r = e % 1024, kt = r / 512, r2 = r % 512, la = r2 >> 3, j = r2 & 7;
      int n = nt * 16 + (la & 15), k = kt * 32 + (la >> 4) * 8 + j;
      v = ld<BF16>(W, l * 8192 + k * 128 + n);
    } else if (o < 32768) {  // Wo
      int e = o - 24576;
      int nt = e / 2048, r = e % 2048, kt = r / 512, r2 = r % 512, la = r2 >> 3, j = r2 & 7;
      int n = nt * 16 + (la & 15), k = kt * 32 + (la >> 4) * 8 + j;
      v = ld<BF16>(Wo, l * 8192 + k * 64 + n);
    } else {  // w1T[e][d] = w1[d][e]
      int e = o - 32768, eo = e / 64, d = e % 64;
      v = ld<BF16>(w1, l * 768 + d * 12 + eo);
    }
  }
  __hip_bfloat16 h = __float2bfloat16(v);
  unsigned short us;
  __builtin_memcpy(&us, &h, 2);
  frag[g] = us;
}

// LDS float offsets
#define O_DM   0      // 1156
#define O_SIN  1156   // 272
#define O_COS  1428   // 272
#define O_ST   1700   // 512
#define O_H    2212   // 2244: H fp32 34x66
#define O_XNF  4456   // 1536: XN A-frags / XNp bf16 34x72
#define O_FF   5992   // 408
#define O_R    6400   // 4616: Q 34x68 + KT 2x64x18 / alias O fp32 34x130
#define O_SCA  11016  // 3072: patch A-frags / SC 2312 / OA frags
#define O_VG   14088  // 4624: V bf16 34x136 + G bf16 34x136
#define SM_TOT 18712

template <bool BF16>
__global__ void __launch_bounds__(512)
vit_fused(const void* __restrict__ x, const void* __restrict__ patch_b,
          const void* __restrict__ cls, const void* __restrict__ pos,
          const void* __restrict__ ln1s, const void* __restrict__ ln1b,
          const void* __restrict__ b1, const void* __restrict__ w2,
          const void* __restrict__ b2, const void* __restrict__ ln2s,
          const void* __restrict__ ln2b, const void* __restrict__ lnfs,
          const void* __restrict__ lnfb, const void* __restrict__ neckw,
          const void* __restrict__ neckb, const void* __restrict__ headw,
          const void* __restrict__ headb, const float* __restrict__ tab,
          const unsigned short* __restrict__ FR, void* __restrict__ out) {
  if ((tab[1700] > 0.5f) != BF16) return;

  const int tid = threadIdx.x;
  const int lane = tid & 63, w = tid >> 6;  // w in 0..7
  const int lq = lane >> 4, ln = lane & 15;
  const int img0 = 2 * blockIdx.x;

  __shared__ __align__(16) float sm[SM_TOT];
  float* sDM  = sm + O_DM;
  float* sSin = sm + O_SIN;
  float* sCos = sm + O_COS;
  float* sST  = sm + O_ST;
  float* sH   = sm + O_H;
  float* sFF  = sm + O_FF;
  float* sQ   = sm + O_R;          // 34x68
  float* sKT  = sm + O_R + 2312;   // 2 x 64x18
  float* sO   = sm + O_R;          // alias, 34x130
  float* sSC  = sm + O_SCA;        // 2312
  unsigned short* sVb = (unsigned short*)(sm + O_VG);          // 34x136
  unsigned short* sGb = (unsigned short*)(sm + O_VG) + 4624;   // 34x136
  const bf16x8* FRB = (const bf16x8*)FR;

  // ---- stage tables + patch A-frags + cls rows ----
  for (int i = tid; i < 1156; i += 512) sDM[i] = tab[544 + i];
  for (int i = tid; i < 272; i += 512) { sSin[i] = tab[i]; sCos[i] = tab[272 + i]; }
  for (int s = tid; s < 768; s += 512) {  // patch A-frags into O_SCA
    int mt = s / 384, r = s % 384, kt = r / 64, la = r % 64;
    int p = la & 15, q = la >> 4;
    int kb = kt * 32 + q * 8;
    int c = kb >> 6, rem = kb & 63, a = rem >> 3;
    int pi = p >> 2, pj = p & 3;
    int src = (img0 + mt) * 3072 + c * 1024 + (pi * 8 + a) * 32 + pj * 8;
    float v[8];
#pragma unroll
    for (int t2 = 0; t2 < 8; t2 += 2) {
      float2 pv = ld2<BF16>(x, src + t2);
      v[t2] = pv.x; v[t2 + 1] = pv.y;
    }
    i32x4 pk;
    pk.x = pack_bf2(v[0], v[1]); pk.y = pack_bf2(v[2], v[3]);
    pk.z = pack_bf2(v[4], v[5]); pk.w = pack_bf2(v[6], v[7]);
    ((i32x4*)(sm + O_SCA))[s] = pk;
  }
  if (tid < 128) {  // cls token rows
    int img = tid >> 6, n = tid & 63;
    sH[(img * 17) * 66 + n] = ld<BF16>(cls, n) + ld<BF16>(pos, n);
  }
  __syncthreads();

  // ---- patch embed MFMA: 8 jobs = 2mt x 4nt, one per wave ----
  {
    int mt = w >> 2, nt = w & 3;
    f32x4 acc = {0.f, 0.f, 0.f, 0.f};
    const bf16x8* paf = (const bf16x8*)(sm + O_SCA);
#pragma unroll
    for (int kt = 0; kt < 6; ++kt)
      acc = MFMA(paf[(mt * 6 + kt) * 64 + lane], FRB[(nt * 6 + kt) * 64 + lane], acc, 0, 0, 0);
    int n = nt * 16 + ln;
    float pb = ld<BF16>(patch_b, n);
#pragma unroll
    for (int i = 0; i < 4; ++i) {
      int t = 1 + lq * 4 + i;
      sH[(mt * 17 + t) * 66 + n] = acc[i] + pb + ld<BF16>(pos, t * 64 + n);
    }
  }
  __syncthreads();

  for (int l = 0; l < NLAY; ++l) {
    const int LB = 1536 + l * 4192;  // layer base, bf16x8 slots

    // ---- ln1 stats: 8 lanes per row + shuffle reduce ----
    if (tid < 272) {
      int m = tid >> 3, sub = tid & 7;
      const float* hp = sH + m * 66 + sub * 8;
      float s1 = 0.f, s2 = 0.f;
#pragma unroll
      for (int i = 0; i < 8; ++i) { float v = hp[i]; s1 += v; s2 += v * v; }
      s1 += __shfl_xor(s1, 1); s2 += __shfl_xor(s2, 1);
      s1 += __shfl_xor(s1, 2); s2 += __shfl_xor(s2, 2);
      s1 += __shfl_xor(s1, 4); s2 += __shfl_xor(s2, 4);
      if (sub == 0) {
        float mu = s1 * (1.f / 64.f);
        float var = s2 * (1.f / 64.f) - mu * mu;
        sST[m] = mu;
        sST[34 + m] = rsqrtf(var + 1e-5f);
      }
    }
    __syncthreads();

    // ---- ln1 -> XN A-frags (bf16) ----
    for (int s = tid; s < 384; s += 512) {
      int mt = s >> 7, kt = (s >> 6) & 1, la = s & 63;
      int m = mt * 16 + (la & 15), q = la >> 4;
      int kb = kt * 32 + q * 8;
      i32x4 pk = {0, 0, 0, 0};
      if (m < 34) {
        float mu = sST[m], rr = sST[34 + m];
        float vv[8];
#pragma unroll
        for (int t2 = 0; t2 < 8; t2 += 2) {
          float2 sv = ld2<BF16>(ln1s, l * 64 + kb + t2);
          float2 bv = ld2<BF16>(ln1b, l * 64 + kb + t2);
          vv[t2]     = (sH[m * 66 + kb + t2] - mu) * rr * sv.x + bv.x;
          vv[t2 + 1] = (sH[m * 66 + kb + t2 + 1] - mu) * rr * sv.y + bv.y;
        }
        pk.x = pack_bf2(vv[0], vv[1]); pk.y = pack_bf2(vv[2], vv[3]);
        pk.z = pack_bf2(vv[4], vv[5]); pk.w = pack_bf2(vv[6], vv[7]);
      }
      ((i32x4*)(sm + O_XNF))[s] = pk;
    }
    __syncthreads();

    // ---- QKVG MFMA: 72 jobs / 8 waves ----
    {
      const bf16x8* xnf = (const bf16x8*)(sm + O_XNF);
      for (int j = w; j < 72; j += 8) {
        int mt = j / 24, nt = j % 24;
        const bf16x8* wf; int ntl, dst;
        if (nt < 4)       { wf = FRB + LB;        ntl = nt;      dst = 0; }
        else if (nt < 8)  { wf = FRB + LB + 512;  ntl = nt - 4;  dst = 1; }
        else if (nt < 16) { wf = FRB + LB + 1024; ntl = nt - 8;  dst = 2; }
        else              { wf = FRB + LB + 2048; ntl = nt - 16; dst = 3; }
        f32x4 acc = {0.f, 0.f, 0.f, 0.f};
#pragma unroll
        for (int kt = 0; kt < 2; ++kt)
          acc = MFMA(xnf[(mt * 2 + kt) * 64 + lane], wf[(ntl * 2 + kt) * 64 + lane], acc, 0, 0, 0);
        int n = ntl * 16 + ln;
        if (dst == 0) {
#pragma unroll
          for (int i = 0; i < 4; ++i) {
            int m = mt * 16 + lq * 4 + i;
            if (m < 34) sQ[m * 68 + n] = acc[i];
          }
        } else if (dst == 1) {
#pragma unroll
          for (int i = 0; i < 4; ++i) {
            int m = mt * 16 + lq * 4 + i;
            if (m < 34) {
              int img = (m >= 17), t = m - img * 17;
              sKT[img * 1152 + n * 18 + t] = acc[i];
            }
          }
        } else {
          unsigned short* db = (dst == 2) ? sVb : sGb;
#pragma unroll
          for (int i = 0; i < 4; ++i) {
            int m = mt * 16 + lq * 4 + i;
            if (m < 34) {
              __hip_bfloat16 hv = __float2bfloat16(acc[i]);
              unsigned short us;
              __builtin_memcpy(&us, &hv, 2);
              db[m * 136 + n] = us;
            }
          }
        }
      }
    }
    __syncthreads();

    // ---- rotary: Q (linear) + KT (transposed, *0.25) ----
    for (int idx = tid; idx < 2176; idx += 512) {
      if (idx < 1088) {
        int m = idx >> 5, pr = idx & 31, d0 = 2 * pr;
        int t = m % 17;
        float sv = sSin[t * 16 + (d0 & 15)], cv = sCos[t * 16 + (d0 & 15)];
        float x0 = sQ[m * 68 + d0], x1 = sQ[m * 68 + d0 + 1];
        sQ[m * 68 + d0]     = x0 * cv - x1 * sv;
        sQ[m * 68 + d0 + 1] = x1 * cv + x0 * sv;
      } else {
        int r = idx - 1088;
        int img = r / 544, r2 = r % 544, pr = r2 / 17, t = r2 % 17, d0 = 2 * pr;
        float sv = sSin[t * 16 + (d0 & 15)], cv = sCos[t * 16 + (d0 & 15)];
        int a0 = img * 1152 + d0 * 18 + t, a1 = a0 + 18;
        float x0 = sKT[a0], x1 = sKT[a1];
        sKT[a0] = (x0 * cv - x1 * sv) * 0.25f;
        sKT[a1] = (x1 * cv + x0 * sv) * 0.25f;
      }
    }
    __syncthreads();

    // ---- scores, u-pairs: 1224 jobs, each writes (u0,u0+1) ----
    for (int idx = tid; idx < 1224; idx += 512) {
      int up = idx % 9, rest = idx / 9;
      int t = rest % 17, rest2 = rest / 17;
      int hh = rest2 & 3, img = rest2 >> 2;
      int u0 = 2 * up, u1 = u0 + 1;
      int dmb = hh * 289 + t * 17;
      int scb = img * 1156 + dmb;
      float out0 = 0.f, out1 = 0.f;
      if (u0 <= t) {
        const float* kp = sKT + img * 1152 + hh * 288 + u0;
        const float4* q4 = (const float4*)(sQ + (img * 17 + t) * 68 + hh * 16);
        float4 qa = q4[0], qb = q4[1], qc = q4[2], qd = q4[3];
        float a0, a1;
        float2 kv;
        kv = *(const float2*)(kp + 0);   a0  = qa.x * kv.x; a1  = qa.x * kv.y;
        kv = *(const float2*)(kp + 18);  a0 += qa.y * kv.x; a1 += qa.y * kv.y;
        kv = *(const float2*)(kp + 36);  a0 += qa.z * kv.x; a1 += qa.z * kv.y;
        kv = *(const float2*)(kp + 54);  a0 += qa.w * kv.x; a1 += qa.w * kv.y;
        kv = *(const float2*)(kp + 72);  a0 += qb.x * kv.x; a1 += qb.x * kv.y;
        kv = *(const float2*)(kp + 90);  a0 += qb.y * kv.x; a1 += qb.y * kv.y;
        kv = *(const float2*)(kp + 108); a0 += qb.z * kv.x; a1 += qb.z * kv.y;
        kv = *(const float2*)(kp + 126); a0 += qb.w * kv.x; a1 += qb.w * kv.y;
        kv = *(const float2*)(kp + 144); a0 += qc.x * kv.x; a1 += qc.x * kv.y;
        kv = *(const float2*)(kp + 162); a0 += qc.y * kv.x; a1 += qc.y * kv.y;
        kv = *(const float2*)(kp + 180); a0 += qc.z * kv.x; a1 += qc.z * kv.y;
        kv = *(const float2*)(kp + 198); a0 += qc.w * kv.x; a1 += qc.w * kv.y;
        kv = *(const float2*)(kp + 216); a0 += qd.x * kv.x; a1 += qd.x * kv.y;
        kv = *(const float2*)(kp + 234); a0 += qd.y * kv.x; a1 += qd.y * kv.y;
        kv = *(const float2*)(kp + 252); a0 += qd.z * kv.x; a1 += qd.z * kv.y;
        kv = *(const float2*)(kp + 270); a0 += qd.w * kv.x; a1 += qd.w * kv.y;
        out0 = a0 * sDM[dmb + u0];
        if (u1 <= t) out1 = a1 * sDM[dmb + u1];
      }
      sSC[scb + u0] = out0;
      if (u1 < 17) sSC[scb + u1] = out1;
    }
    __syncthreads();

    // ---- denominators ----
    if (tid < 136) {
      const float* base = sSC + tid * 17;
      float s = 0.f;
      for (int u = 0; u < 17; ++u) s += base[u];
      float den = fabsf(s);
      if (den < 1.f) den = 1.f;
      sST[68 + tid] = 1.f / den;
    }
    __syncthreads();

    // ---- AV, j-pairs: 2176 jobs, V read as b32 pair ----
    for (int idx = tid; idx < 2176; idx += 512) {
      int img = idx / 1088, r = idx % 1088;
      int hh = r / 272, r2 = r % 272, t = r2 >> 4, jp = r2 & 15;
      int c0 = hh * 32 + jp * 2;
      int m = img * 17 + t;
      const float* sc = sSC + img * 1156 + hh * 289 + t * 17;
      const unsigned short* vb = sVb + img * 2312 + c0;
      float a0 = 0.f, a1 = 0.f;
#pragma unroll
      for (int u = 0; u < 17; ++u) {
        float2 vv = unpk(*(const unsigned*)(vb + u * 136));
        float s = sc[u];
        a0 += s * vv.x;
        a1 += s * vv.y;
      }
      float den = sST[68 + img * 68 + hh * 17 + t];
      float2 res; res.x = a0 * den; res.y = a1 * den;
      *(float2*)(sO + m * 130 + c0) = res;
    }
    __syncthreads();

    // ---- group norm stats: 2 lanes per row ----
    if (tid < 272) {
      int row = tid >> 1, sub = tid & 1;  // row = img*68 + hh*17 + t
      int img = row / 68, hr = row % 68, hh = hr / 17, t = hr % 17;
      int m = img * 17 + t;
      const float* op = sO + m * 130 + hh * 32 + sub * 16;
      float s1 = 0.f, s2 = 0.f;
#pragma unroll
      for (int i = 0; i < 16; ++i) { float v = op[i]; s1 += v; s2 += v * v; }
      s1 += __shfl_xor(s1, 1); s2 += __shfl_xor(s2, 1);
      if (sub == 0) {
        float mu = s1 * (1.f / 32.f);
        float var = s2 * (1.f / 32.f) - mu * mu;
        sST[204 + row] = mu;
        sST[340 + row] = rsqrtf(var + 1e-5f);
      }
    }
    __syncthreads();

    // ---- groupnorm + silu gate -> OA frags ----
    for (int s = tid; s < 768; s += 512) {
      int mt = s >> 8, kt = (s >> 6) & 3, la = s & 63;
      int q = la >> 4, m = mt * 16 + (la & 15);
      int cb = kt * 32 + q * 8;
      i32x4 pk = {0, 0, 0, 0};
      if (m < 34) {
        int img = (m >= 17), t = m - img * 17;
        int sti = img * 68 + kt * 17 + t;
        float mu = sST[204 + sti], rr = sST[340 + sti];
        float vv[8];
#pragma unroll
        for (int q2 = 0; q2 < 8; ++q2) {
          int c = cb + q2;
          float on = (sO[m * 130 + c] - mu) * rr;
          float gv = bfu(sGb[m * 136 + c]);
          vv[q2] = on * (gv / (1.f + __expf(-gv)));
        }
        pk.x = pack_bf2(vv[0], vv[1]); pk.y = pack_bf2(vv[2], vv[3]);
        pk.z = pack_bf2(vv[4], vv[5]); pk.w = pack_bf2(vv[6], vv[7]);
      }
      ((i32x4*)(sm + O_SCA))[s] = pk;
    }
    __syncthreads();

    // ---- Wo MFMA: 12 jobs / 8 waves; += residual ----
    {
      const bf16x8* oaf = (const bf16x8*)(sm + O_SCA);
      const bf16x8* wof = FRB + LB + 3072;
      for (int j = w; j < 12; j += 8) {
        int mt = j / 4, nt = j % 4;
        f32x4 acc = {0.f, 0.f, 0.f, 0.f};
#pragma unroll
        for (int kt = 0; kt < 4; ++kt)
          acc = MFMA(oaf[(mt * 4 + kt) * 64 + lane], wof[(nt * 4 + kt) * 64 + lane], acc, 0, 0, 0);
        int n = nt * 16 + ln;
#pragma unroll
        for (int i = 0; i < 4; ++i) {
          int m = mt * 16 + lq * 4 + i;
          if (m < 34) sH[m * 66 + n] += acc[i];
        }
      }
    }
    __syncthreads();

    // ---- ln2 stats ----
    if (tid < 272) {
      int m = tid >> 3, sub = tid & 7;
      const float* hp = sH + m * 66 + sub * 8;
      float s1 = 0.f, s2 = 0.f;
#pragma unroll
      for (int i = 0; i < 8; ++i) { float v = hp[i]; s1 += v; s2 += v * v; }
      s1 += __shfl_xor(s1, 1); s2 += __shfl_xor(s2, 1);
      s1 += __shfl_xor(s1, 2); s2 += __shfl_xor(s2, 2);
      s1 += __shfl_xor(s1, 4); s2 += __shfl_xor(s2, 4);
      if (sub == 0) {
        float mu = s1 * (1.f / 64.f);
        float var = s2 * (1.f / 64.f) - mu * mu;
        sST[m] = mu;
        sST[34 + m] = rsqrtf(var + 1e-5f);
      }
    }
    __syncthreads();

    // ---- ln2 -> XNp plain bf16 (34 x pitch 72) ----
    for (int idx = tid; idx < 1088; idx += 512) {
      int m = idx >> 5, dp = idx & 31, d0 = 2 * dp;
      float mu = sST[m], rr = sST[34 + m];
      float2 sv = ld2<BF16>(ln2s, l * 64 + d0);
      float2 bv = ld2<BF16>(ln2b, l * 64 + d0);
      float a0 = (sH[m * 66 + d0] - mu) * rr * sv.x + bv.x;
      float a1 = (sH[m * 66 + d0 + 1] - mu) * rr * sv.y + bv.y;
      ((unsigned*)(sm + O_XNF))[m * 36 + dp] = pack_bf2(a0, a1);
    }
    __syncthreads();

    // ---- FFN1 (64->12) + gelu ----
    for (int item = tid; item < 408; item += 512) {
      int m = item / 12, e = item % 12;
      float acc = ld<BF16>(b1, l * 12 + e);
      const float4* xp4 = (const float4*)(sm + O_XNF);
      const i32x4* w1t = (const i32x4*)(FR + 12288 + l * 33536 + 32768 + e * 64);
#pragma unroll
      for (int d4 = 0; d4 < 8; ++d4) {
        float4 xv = xp4[m * 9 + d4];
        i32x4 wv = w1t[d4];
        float2 xa = unpk(__float_as_uint(xv.x)), wa = unpk((unsigned)wv.x);
        float2 xb = unpk(__float_as_uint(xv.y)), wb = unpk((unsigned)wv.y);
        float2 xc = unpk(__float_as_uint(xv.z)), wc = unpk((unsigned)wv.z);
        float2 xd = unpk(__float_as_uint(xv.w)), wd = unpk((unsigned)wv.w);
        acc += xa.x * wa.x + xa.y * wa.y + xb.x * wb.x + xb.y * wb.y
             + xc.x * wc.x + xc.y * wc.y + xd.x * wd.x + xd.y * wd.y;
      }
      float inner = 0.7978845608028654f * (acc + 0.044715f * acc * acc * acc);
      sFF[item] = 0.5f * acc * (1.f + tanhf(inner));
    }
    __syncthreads();

    // ---- FFN2 (12->64) + residual ----
    for (int idx = tid; idx < 1088; idx += 512) {
      int m = idx >> 5, dp = idx & 31, d0 = 2 * dp;
      float2 bv = ld2<BF16>(b2, l * 64 + d0);
      float a0 = bv.x, a1 = bv.y;
      const float* ff = sFF + m * 12;
#pragma unroll
      for (int e = 0; e < 12; ++e) {
        float2 wv = ld2<BF16>(w2, (l * 12 + e) * 64 + d0);
        a0 += ff[e] * wv.x;
        a1 += ff[e] * wv.y;
      }
      sH[m * 66 + d0] += a0;
      sH[m * 66 + d0 + 1] += a1;
    }
    __syncthreads();
  }

  // ---- final: lnf (last token each image), neck, head ----
  if (tid < 2) {
    int m = tid * 17 + 16;
    float s1 = 0.f, s2 = 0.f;
    for (int d = 0; d < 64; ++d) {
      float v = sH[m * 66 + d];
      s1 += v; s2 += v * v;
    }
    float mu = s1 * (1.f / 64.f);
    float var = s2 * (1.f / 64.f) - mu * mu;
    sST[tid] = mu;
    sST[2 + tid] = rsqrtf(var + 1e-5f);
  }
  __syncthreads();
  if (tid < 32) {
    int img = tid >> 4, jn = tid & 15;
    int m = img * 17 + 16;
    float mu = sST[img], rr = sST[2 + img];
    float acc = ld<BF16>(neckb, jn);
    for (int d = 0; d < 64; ++d) {
      float yn = (sH[m * 66 + d] - mu) * rr * ld<BF16>(lnfs, d) + ld<BF16>(lnfb, d);
      acc += yn * ld<BF16>(neckw, d * 16 + jn);
    }
    sST[8 + img * 16 + jn] = acc;
  }
  __syncthreads();
  if (tid < 20) {
    int img = tid / 10, o = tid % 10;
    float acc = ld<BF16>(headb, o);
#pragma unroll
    for (int e = 0; e < 16; ++e) acc += sST[8 + img * 16 + e] * ld<BF16>(headw, e * 10 + o);
    if (BF16) {
      ((__hip_bfloat16*)out)[(img0 + img) * 10 + o] = __float2bfloat16(acc);
    } else {
      ((float*)out)[(img0 + img) * 10 + o] = acc;
    }
  }
}

extern "C" void kernel_launch(void* const* d_in, const int* in_sizes, int n_in,
                              void* d_out, int out_size, void* d_ws, size_t ws_size,
                              hipStream_t stream) {
  float* tab = (float*)d_ws;
  unsigned short* frag = (unsigned short*)((char*)d_ws + 8192);

  setup_tables<<<dim3(1), dim3(256), 0, stream>>>(tab, d_in[0]);

  const int prepBlocks = (FRAG_TOT + 255) / 256;
  prep_frags<false><<<dim3(prepBlocks), dim3(256), 0, stream>>>(
      d_in[1], d_in[5], d_in[6], d_in[7], d_in[8], d_in[9], d_in[12], tab, frag);
  prep_frags<true><<<dim3(prepBlocks), dim3(256), 0, stream>>>(
      d_in[1], d_in[5], d_in[6], d_in[7], d_in[8], d_in[9], d_in[12], tab, frag);

  const int B = in_sizes[0] / 3072;
  const int grid = B / 2;

  vit_fused<false><<<dim3(grid), dim3(512), 0, stream>>>(
      d_in[0], d_in[2], d_in[3], d_in[4], d_in[10], d_in[11], d_in[13],
      d_in[14], d_in[15], d_in[16], d_in[17], d_in[18], d_in[19], d_in[20],
      d_in[21], d_in[22], d_in[23], tab, frag, d_out);
  vit_fused<true><<<dim3(grid), dim3(512), 0, stream>>>(
      d_in[0], d_in[2], d_in[3], d_in[4], d_in[10], d_in[11], d_in[13],
      d_in[14], d_in[15], d_in[16], d_in[17], d_in[18], d_in[19], d_in[20],
      d_in[21], d_in[22], d_in[23], tab, frag, d_out);
}